// Round 1
// baseline (145.157 us; speedup 1.0000x reference)
//
#include <hip/hip_runtime.h>

#define B_SZ 1024
#define F_SZ 32
#define D_SZ 128
#define FD   (F_SZ * D_SZ)      // 4096, stride of one b-row of feature
#define LDA  136                // 128 + 8 pad (shorts): keeps b128 frag reads 16B-aligned, ~conflict-free
#define LDB  136

typedef __bf16 bf16x8 __attribute__((ext_vector_type(8)));
typedef float floatx4 __attribute__((ext_vector_type(4)));

__device__ __forceinline__ unsigned short f2bf(float f) {
  // round-to-nearest-even fp32 -> bf16 (no NaN inputs here)
  unsigned u = __float_as_uint(f);
  u += 0x7fffu + ((u >> 16) & 1u);
  return (unsigned short)(u >> 16);
}

__device__ __forceinline__ float bf2f(unsigned short h) {
  return __uint_as_float(((unsigned)h) << 16);
}

// One workgroup per strict-upper pair (i<j). 256 threads = 4 waves.
// Loops over 8 b-tiles of 128 rows. Per tile: Y = bf16(f_i) @ bf16(Z_ij)
// via mfma_f32_16x16x32_bf16 (wave tile 32 rows x 128 cols), then
// out[b] = sum_e Y[b,e] * f_j[b,e] with a 16-lane butterfly.
__global__ __launch_bounds__(256, 2)
void interaction_pair_kernel(const float* __restrict__ feat,
                             const float* __restrict__ mat,
                             float* __restrict__ out) {
  __shared__ unsigned short sA[128 * LDA];   // bf16(f_i tile), [b][d]
  __shared__ unsigned short sBT[128 * LDB];  // bf16(Z^T),      [e][d]

  const int t    = threadIdx.x;
  const int w    = t >> 6;        // wave 0..3
  const int lane = t & 63;
  const int l15  = lane & 15;
  const int quad = lane >> 4;

  // decode blockIdx -> (i, j), i < j
  int p = blockIdx.x;
  int i = 0;
  while (p >= F_SZ - 1 - i) { p -= F_SZ - 1 - i; ++i; }
  const int j = i + 1 + p;

  // ---- stage Z^T (once per block): fused sigmoid/stretch/clip + bf16 ----
  {
    const float* zp = mat + (((size_t)i * F_SZ + j) * (size_t)(D_SZ * D_SZ));
    #pragma unroll 8
    for (int it = 0; it < 64; ++it) {
      int idx = it * 256 + t;          // e fastest -> coalesced global read
      int d = idx >> 7, e = idx & 127;
      float v = zp[idx];
      float s = 1.0f / (1.0f + __expf(-v));
      float z = fminf(1.0f, fmaxf(0.0f, fmaf(s, 1.2f, -0.1f)));
      sBT[e * LDB + d] = f2bf(z);      // transposed store
    }
  }

  for (int bt = 0; bt < 8; ++bt) {
    const int b0 = bt * 128;

    // ---- stage f_i tile as bf16 (coalesced float4 reads, b64 LDS writes) ----
    #pragma unroll 4
    for (int it = 0; it < 16; ++it) {
      int idx4 = it * 256 + t;         // 4096 float4 groups
      int r = idx4 >> 5, c4 = idx4 & 31;
      const float4 v = *(const float4*)(feat + (size_t)(b0 + r) * FD + i * D_SZ + c4 * 4);
      ushort4 h;
      h.x = f2bf(v.x); h.y = f2bf(v.y); h.z = f2bf(v.z); h.w = f2bf(v.w);
      *(ushort4*)(&sA[r * LDA + c4 * 4]) = h;
    }
    __syncthreads();

    // ---- MFMA: Y[32 x 128] per wave, K = 128 in 4 steps ----
    floatx4 acc[2][8];
    #pragma unroll
    for (int mf = 0; mf < 2; ++mf)
      #pragma unroll
      for (int nf = 0; nf < 8; ++nf)
        acc[mf][nf] = (floatx4){0.f, 0.f, 0.f, 0.f};

    #pragma unroll
    for (int k0 = 0; k0 < 128; k0 += 32) {
      const int kc = k0 + quad * 8;
      bf16x8 a0 = *(const bf16x8*)&sA[(w * 32 +      l15) * LDA + kc];
      bf16x8 a1 = *(const bf16x8*)&sA[(w * 32 + 16 + l15) * LDA + kc];
      #pragma unroll
      for (int nf = 0; nf < 8; ++nf) {
        bf16x8 bfr = *(const bf16x8*)&sBT[(nf * 16 + l15) * LDB + kc];
        acc[0][nf] = __builtin_amdgcn_mfma_f32_16x16x32_bf16(a0, bfr, acc[0][nf], 0, 0, 0);
        acc[1][nf] = __builtin_amdgcn_mfma_f32_16x16x32_bf16(a1, bfr, acc[1][nf], 0, 0, 0);
      }
    }

    // ---- epilogue: out[b] = sum_e Y[b,e] * f_j[b,e] ----
    // C/D layout (verified m89/m91): col = lane&15, row = quad*4 + reg
    #pragma unroll
    for (int mf = 0; mf < 2; ++mf) {
      float pl[4] = {0.f, 0.f, 0.f, 0.f};
      const int rb = w * 32 + mf * 16 + quad * 4;    // local b of reg 0
      #pragma unroll
      for (int nf = 0; nf < 8; ++nf) {
        const int col = nf * 16 + l15;
        const float* fj = feat + (size_t)(b0 + rb) * FD + j * D_SZ + col;
        floatx4 c = acc[mf][nf];
        pl[0] += c[0] * fj[0];
        pl[1] += c[1] * fj[FD];
        pl[2] += c[2] * fj[2 * FD];
        pl[3] += c[3] * fj[3 * FD];
      }
      #pragma unroll
      for (int off = 1; off < 16; off <<= 1) {
        pl[0] += __shfl_xor(pl[0], off, 64);
        pl[1] += __shfl_xor(pl[1], off, 64);
        pl[2] += __shfl_xor(pl[2], off, 64);
        pl[3] += __shfl_xor(pl[3], off, 64);
      }
      if (l15 == 0) {
        size_t ob = (size_t)(b0 + rb) * (F_SZ * F_SZ) + (size_t)i * F_SZ + j;
        out[ob]                    = pl[0];
        out[ob + 1 * F_SZ * F_SZ]  = pl[1];
        out[ob + 2 * F_SZ * F_SZ]  = pl[2];
        out[ob + 3 * F_SZ * F_SZ]  = pl[3];
      }
    }
    __syncthreads();  // protect sA before next tile's staging
  }
}

extern "C" void kernel_launch(void* const* d_in, const int* in_sizes, int n_in,
                              void* d_out, int out_size, void* d_ws, size_t ws_size,
                              hipStream_t stream) {
  const float* feat = (const float*)d_in[0];   // [B, F, D] fp32
  const float* mat  = (const float*)d_in[1];   // [F, F, D, D] fp32
  float* out = (float*)d_out;                  // [B, F, F] fp32

  // zero the whole output (diagonal + lower triangle stay 0; d_out is re-poisoned)
  hipMemsetAsync(out, 0, (size_t)out_size * sizeof(float), stream);

  const int n_pairs = F_SZ * (F_SZ - 1) / 2;   // 496
  interaction_pair_kernel<<<dim3(n_pairs), dim3(256), 0, stream>>>(feat, mat, out);
}